// Round 1
// baseline (2911.034 us; speedup 1.0000x reference)
//
#include <hip/hip_runtime.h>

// GraphConvolution: out = segment_sum(edge_val * (x@W)[edge_col], edge_row) + b
// M=100000 nodes, K=256 in_feats, N=128 out_feats, E=1.6M edges. All fp32.

#define K_FEATS 256
#define N_FEATS 128

// ---------------- GEMM: sup = x @ W ----------------
// Block: 256 threads, computes 64 rows x 128 cols.
// Thread tid: col-quad cq = tid&31 (4 cols), row-base rb = tid>>5 (8 rows, stride 8).
__global__ __launch_bounds__(256) void gcn_gemm(const float* __restrict__ x,
                                                const float* __restrict__ w,
                                                float* __restrict__ sup, int M) {
    __shared__ float Ws[32][128];   // 16 KB, K-chunk of W
    __shared__ float Xs[64][36];    // 9 KB, pad to 36 floats (16B-aligned rows, bank spread)

    const int tid  = threadIdx.x;
    const int row0 = blockIdx.x * 64;
    const int cq   = tid & 31;
    const int rb   = tid >> 5;

    float acc[8][4];
#pragma unroll
    for (int i = 0; i < 8; i++)
#pragma unroll
        for (int j = 0; j < 4; j++) acc[i][j] = 0.f;

    for (int k0 = 0; k0 < K_FEATS; k0 += 32) {
        // stage W chunk: 32 rows x 128 cols = 1024 float4 / 256 threads = 4 each
#pragma unroll
        for (int l = 0; l < 4; l++) {
            int f  = tid + l * 256;      // float4 index
            int kk = f >> 5;
            int c4 = f & 31;
            float4 v = *(const float4*)(w + (k0 + kk) * N_FEATS + c4 * 4);
            *(float4*)(&Ws[kk][c4 * 4]) = v;
        }
        // stage X chunk: 64 rows x 32 k = 512 float4 / 256 threads = 2 each
#pragma unroll
        for (int l = 0; l < 2; l++) {
            int f  = tid + l * 256;
            int r  = f >> 3;
            int k4 = f & 7;
            int grow = row0 + r;
            float4 v = make_float4(0.f, 0.f, 0.f, 0.f);
            if (grow < M) v = *(const float4*)(x + (long)grow * K_FEATS + k0 + k4 * 4);
            *(float4*)(&Xs[r][k4 * 4]) = v;
        }
        __syncthreads();

#pragma unroll
        for (int kk = 0; kk < 32; kk++) {
            float4 wv = *(const float4*)(&Ws[kk][cq * 4]);
#pragma unroll
            for (int i = 0; i < 8; i++) {
                float xv = Xs[rb + i * 8][kk];
                acc[i][0] += xv * wv.x;
                acc[i][1] += xv * wv.y;
                acc[i][2] += xv * wv.z;
                acc[i][3] += xv * wv.w;
            }
        }
        __syncthreads();
    }

#pragma unroll
    for (int i = 0; i < 8; i++) {
        int grow = row0 + rb + i * 8;
        if (grow < M) {
            *(float4*)(sup + (long)grow * N_FEATS + cq * 4) =
                make_float4(acc[i][0], acc[i][1], acc[i][2], acc[i][3]);
        }
    }
}

// ---------------- bias init: out[i][j] = b[j] ----------------
__global__ __launch_bounds__(256) void gcn_bias_init(const float* __restrict__ b,
                                                     float* __restrict__ out, int total4) {
    int t = blockIdx.x * 256 + threadIdx.x;
    if (t < total4) {
        const float4* b4 = (const float4*)b;
        ((float4*)out)[t] = b4[t & 31];   // N_FEATS/4 = 32
    }
}

// ---------------- scatter: out[row] += val * sup[col] ----------------
// 32 threads per edge, each handles a float4 (4 cols).
__global__ __launch_bounds__(256) void gcn_scatter(const int* __restrict__ erow,
                                                   const int* __restrict__ ecol,
                                                   const float* __restrict__ eval_,
                                                   const float* __restrict__ sup,
                                                   float* __restrict__ out, long total) {
    long t = (long)blockIdx.x * 256 + threadIdx.x;
    if (t >= total) return;
    int e = (int)(t >> 5);
    int q = (int)(t & 31);
    int r = erow[e];
    int c = ecol[e];
    float v = eval_[e];
    float4 s = *(const float4*)(sup + (long)c * N_FEATS + q * 4);
    float* op = out + (long)r * N_FEATS + q * 4;
    atomicAdd(op + 0, v * s.x);
    atomicAdd(op + 1, v * s.y);
    atomicAdd(op + 2, v * s.z);
    atomicAdd(op + 3, v * s.w);
}

extern "C" void kernel_launch(void* const* d_in, const int* in_sizes, int n_in,
                              void* d_out, int out_size, void* d_ws, size_t ws_size,
                              hipStream_t stream) {
    const float* x     = (const float*)d_in[0];
    const int*   erow  = (const int*)d_in[1];
    const int*   ecol  = (const int*)d_in[2];
    const float* eval_ = (const float*)d_in[3];
    const float* w     = (const float*)d_in[4];
    const float* b     = (const float*)d_in[5];
    float* out = (float*)d_out;
    float* sup = (float*)d_ws;          // M*N fp32 = 51.2 MB scratch

    const int M = in_sizes[0] / K_FEATS;   // 100000
    const int E = in_sizes[1];             // 1600000

    // sup = x @ W
    gcn_gemm<<<(M + 63) / 64, 256, 0, stream>>>(x, w, sup, M);

    // out = b (broadcast)
    int total4 = M * (N_FEATS / 4);
    gcn_bias_init<<<(total4 + 255) / 256, 256, 0, stream>>>(b, out, total4);

    // out[row] += val * sup[col]
    long total = (long)E * 32;
    int blocks = (int)((total + 255) / 256);
    gcn_scatter<<<blocks, 256, 0, stream>>>(erow, ecol, eval_, sup, out, total);
}

// Round 2
// 542.941 us; speedup vs baseline: 5.3616x; 5.3616x over previous
//
#include <hip/hip_runtime.h>

// GraphConvolution: out = segment_sum(edge_val * (x@W)[edge_col], edge_row) + b
// M=100000 nodes, K=256 in_feats, N=128 out_feats, E=1.6M edges. All fp32.
//
// R2 strategy: kill the 204.8M fp32 atomics (R1: WRITE_SIZE 3.2GB, 64x amp).
// Device-side counting sort by destination row -> wave-per-row segmented
// reduce with registers, single write per output row, bias fused.

#define K_FEATS 256
#define N_FEATS 128

// ---------------- GEMM: sup = x @ W ----------------
__global__ __launch_bounds__(256) void gcn_gemm(const float* __restrict__ x,
                                                const float* __restrict__ w,
                                                float* __restrict__ sup, int M) {
    __shared__ float Ws[32][128];
    __shared__ float Xs[64][36];

    const int tid  = threadIdx.x;
    const int row0 = blockIdx.x * 64;
    const int cq   = tid & 31;
    const int rb   = tid >> 5;

    float acc[8][4];
#pragma unroll
    for (int i = 0; i < 8; i++)
#pragma unroll
        for (int j = 0; j < 4; j++) acc[i][j] = 0.f;

    for (int k0 = 0; k0 < K_FEATS; k0 += 32) {
#pragma unroll
        for (int l = 0; l < 4; l++) {
            int f  = tid + l * 256;
            int kk = f >> 5;
            int c4 = f & 31;
            float4 v = *(const float4*)(w + (k0 + kk) * N_FEATS + c4 * 4);
            *(float4*)(&Ws[kk][c4 * 4]) = v;
        }
#pragma unroll
        for (int l = 0; l < 2; l++) {
            int f  = tid + l * 256;
            int r  = f >> 3;
            int k4 = f & 7;
            int grow = row0 + r;
            float4 v = make_float4(0.f, 0.f, 0.f, 0.f);
            if (grow < M) v = *(const float4*)(x + (long)grow * K_FEATS + k0 + k4 * 4);
            *(float4*)(&Xs[r][k4 * 4]) = v;
        }
        __syncthreads();

#pragma unroll
        for (int kk = 0; kk < 32; kk++) {
            float4 wv = *(const float4*)(&Ws[kk][cq * 4]);
#pragma unroll
            for (int i = 0; i < 8; i++) {
                float xv = Xs[rb + i * 8][kk];
                acc[i][0] += xv * wv.x;
                acc[i][1] += xv * wv.y;
                acc[i][2] += xv * wv.z;
                acc[i][3] += xv * wv.w;
            }
        }
        __syncthreads();
    }

#pragma unroll
    for (int i = 0; i < 8; i++) {
        int grow = row0 + rb + i * 8;
        if (grow < M) {
            *(float4*)(sup + (long)grow * N_FEATS + cq * 4) =
                make_float4(acc[i][0], acc[i][1], acc[i][2], acc[i][3]);
        }
    }
}

// ---------------- counting sort by edge_row ----------------
__global__ __launch_bounds__(256) void zero_counts(int* __restrict__ counts, int M) {
    int i = blockIdx.x * 256 + threadIdx.x;
    if (i <= M) counts[i] = 0;
}

__global__ __launch_bounds__(256) void hist_rows(const int* __restrict__ erow,
                                                 int* __restrict__ counts, int E) {
    int e = blockIdx.x * 256 + threadIdx.x;
    if (e < E) atomicAdd(&counts[erow[e]], 1);
}

// Per-1024-chunk exclusive scan; block totals to blocksums.
__global__ __launch_bounds__(1024) void scan_blocks(const int* __restrict__ counts,
                                                    int* __restrict__ tmp_ex,
                                                    int* __restrict__ blocksums, int M) {
    __shared__ int sm[1024];
    int t = threadIdx.x;
    int idx = blockIdx.x * 1024 + t;
    int v = (idx < M) ? counts[idx] : 0;
    sm[t] = v;
    __syncthreads();
#pragma unroll
    for (int s = 1; s < 1024; s <<= 1) {
        int a = (t >= s) ? sm[t - s] : 0;
        __syncthreads();
        sm[t] += a;
        __syncthreads();
    }
    if (idx < M) tmp_ex[idx] = sm[t] - v;
    if (t == 1023) blocksums[blockIdx.x] = sm[1023];
}

// Single-block exclusive scan of block sums (nb <= 1024).
__global__ __launch_bounds__(1024) void scan_sums(int* __restrict__ blocksums, int nb) {
    __shared__ int sm[1024];
    int t = threadIdx.x;
    int v = (t < nb) ? blocksums[t] : 0;
    sm[t] = v;
    __syncthreads();
#pragma unroll
    for (int s = 1; s < 1024; s <<= 1) {
        int a = (t >= s) ? sm[t - s] : 0;
        __syncthreads();
        sm[t] += a;
        __syncthreads();
    }
    if (t < nb) blocksums[t] = sm[t] - v;   // exclusive
}

// off0[i] = final exclusive offset; off1[i] = same (consumed as atomic cursor).
__global__ __launch_bounds__(256) void add_offsets(int* __restrict__ off0,
                                                   int* __restrict__ off1,
                                                   const int* __restrict__ blocksums, int M) {
    int i = blockIdx.x * 256 + threadIdx.x;
    if (i < M) {
        int v = off0[i] + blocksums[i >> 10];
        off0[i] = v;
        off1[i] = v;
    }
}

// Scatter edges to sorted position; pack (col, val) as int2.
__global__ __launch_bounds__(256) void fill_sorted(const int* __restrict__ erow,
                                                   const int* __restrict__ ecol,
                                                   const float* __restrict__ eval_,
                                                   int* __restrict__ cursor,
                                                   int2* __restrict__ sedge, int E) {
    int e = blockIdx.x * 256 + threadIdx.x;
    if (e < E) {
        int r = erow[e];
        int p = atomicAdd(&cursor[r], 1);
        sedge[p] = make_int2(ecol[e], __float_as_int(eval_[e]));
    }
}

// ---------------- SpMM: wave per row, registers, no atomics ----------------
// After fill_sorted, off1[r] == row end (off0[r] + count[r]).
__global__ __launch_bounds__(256) void gcn_spmm(const int* __restrict__ off0,
                                                const int* __restrict__ off1,
                                                const int2* __restrict__ sedge,
                                                const float* __restrict__ sup,
                                                const float* __restrict__ b,
                                                float* __restrict__ out, int M) {
    int row  = blockIdx.x * 4 + (threadIdx.x >> 6);
    int lane = threadIdx.x & 63;
    if (row >= M) return;
    int s = off0[row], e = off1[row];
    const float2* sup2 = (const float2*)sup;
    float2 acc = make_float2(0.f, 0.f);
    int i = s;
    for (; i + 1 < e; i += 2) {
        int2 e0 = sedge[i];
        int2 e1 = sedge[i + 1];
        float v0 = __int_as_float(e0.y);
        float v1 = __int_as_float(e1.y);
        float2 a0 = sup2[(long)e0.x * 64 + lane];
        float2 a1 = sup2[(long)e1.x * 64 + lane];
        acc.x += v0 * a0.x;
        acc.y += v0 * a0.y;
        acc.x += v1 * a1.x;
        acc.y += v1 * a1.y;
    }
    if (i < e) {
        int2 e0 = sedge[i];
        float v0 = __int_as_float(e0.y);
        float2 a0 = sup2[(long)e0.x * 64 + lane];
        acc.x += v0 * a0.x;
        acc.y += v0 * a0.y;
    }
    float2 bb = ((const float2*)b)[lane];
    ((float2*)out)[(long)row * 64 + lane] = make_float2(acc.x + bb.x, acc.y + bb.y);
}

// ---------------- fallback (atomic) path, if ws too small ----------------
__global__ __launch_bounds__(256) void gcn_bias_init(const float* __restrict__ b,
                                                     float* __restrict__ out, int total4) {
    int t = blockIdx.x * 256 + threadIdx.x;
    if (t < total4) {
        const float4* b4 = (const float4*)b;
        ((float4*)out)[t] = b4[t & 31];
    }
}

__global__ __launch_bounds__(256) void gcn_scatter(const int* __restrict__ erow,
                                                   const int* __restrict__ ecol,
                                                   const float* __restrict__ eval_,
                                                   const float* __restrict__ sup,
                                                   float* __restrict__ out, long total) {
    long t = (long)blockIdx.x * 256 + threadIdx.x;
    if (t >= total) return;
    int e = (int)(t >> 5);
    int q = (int)(t & 31);
    int r = erow[e];
    int c = ecol[e];
    float v = eval_[e];
    float4 s = *(const float4*)(sup + (long)c * N_FEATS + q * 4);
    float* op = out + (long)r * N_FEATS + q * 4;
    atomicAdd(op + 0, v * s.x);
    atomicAdd(op + 1, v * s.y);
    atomicAdd(op + 2, v * s.z);
    atomicAdd(op + 3, v * s.w);
}

extern "C" void kernel_launch(void* const* d_in, const int* in_sizes, int n_in,
                              void* d_out, int out_size, void* d_ws, size_t ws_size,
                              hipStream_t stream) {
    const float* x     = (const float*)d_in[0];
    const int*   erow  = (const int*)d_in[1];
    const int*   ecol  = (const int*)d_in[2];
    const float* eval_ = (const float*)d_in[3];
    const float* w     = (const float*)d_in[4];
    const float* b     = (const float*)d_in[5];
    float* out = (float*)d_out;

    const int M = in_sizes[0] / K_FEATS;   // 100000
    const int E = in_sizes[1];             // 1600000

    // workspace layout (16B aligned)
    size_t o_sup  = 0;
    size_t o_off0 = o_sup  + ((size_t)M * N_FEATS * 4);            // 51,200,000
    size_t o_off1 = o_off0 + (((size_t)(M + 1) * 4 + 15) & ~15ul);
    size_t o_edge = o_off1 + (((size_t)(M + 1) * 4 + 15) & ~15ul);
    size_t o_bs   = o_edge + ((size_t)E * 8);
    size_t need   = o_bs + 4096;

    float* sup = (float*)((char*)d_ws + o_sup);

    // sup = x @ W
    gcn_gemm<<<(M + 63) / 64, 256, 0, stream>>>(x, w, sup, M);

    if (ws_size >= need) {
        int*  off0   = (int*)((char*)d_ws + o_off0);
        int*  off1   = (int*)((char*)d_ws + o_off1);
        int2* sedge  = (int2*)((char*)d_ws + o_edge);
        int*  bsums  = (int*)((char*)d_ws + o_bs);

        int nb = (M + 1023) / 1024;   // 98 chunks

        zero_counts<<<(M + 256) / 256, 256, 0, stream>>>(off1, M);
        hist_rows<<<(E + 255) / 256, 256, 0, stream>>>(erow, off1, E);
        scan_blocks<<<nb, 1024, 0, stream>>>(off1, off0, bsums, M);
        scan_sums<<<1, 1024, 0, stream>>>(bsums, nb);
        add_offsets<<<(M + 255) / 256, 256, 0, stream>>>(off0, off1, bsums, M);
        fill_sorted<<<(E + 255) / 256, 256, 0, stream>>>(erow, ecol, eval_, off1, sedge, E);
        gcn_spmm<<<(M + 3) / 4, 256, 0, stream>>>(off0, off1, sedge, sup, b, out, M);
    } else {
        // fallback: atomic scatter (R1 path)
        int total4 = M * (N_FEATS / 4);
        gcn_bias_init<<<(total4 + 255) / 256, 256, 0, stream>>>(b, out, total4);
        long total = (long)E * 32;
        int blocks = (int)((total + 255) / 256);
        gcn_scatter<<<blocks, 256, 0, stream>>>(erow, ecol, eval_, sup, out, total);
    }
}

// Round 3
// 504.572 us; speedup vs baseline: 5.7693x; 1.0760x over previous
//
#include <hip/hip_runtime.h>

// GraphConvolution: out = segment_sum(edge_val * (x@W)[edge_col], edge_row) + b
// M=100000 nodes, K=256 in_feats, N=128 out_feats, E=1.6M edges. fp32 in/out.
//
// R3: GEMM -> bf16 MFMA (16x16x32), sup stored bf16 (halves spmm gather).
// Sort machinery (counting sort by row) unchanged from R2.

#define K_FEATS 256
#define N_FEATS 128

typedef __attribute__((ext_vector_type(8))) short short8;
typedef __attribute__((ext_vector_type(4))) float float4v;

__device__ __forceinline__ unsigned short f2bf(float f) {
    unsigned int u = __float_as_uint(f);
    unsigned int r = u + 0x7FFF + ((u >> 16) & 1);   // round-to-nearest-even
    return (unsigned short)(r >> 16);
}

// ---------------- prep: Wt[n][k] bf16 from w[k][n] fp32 ----------------
// grid 128 (n), block 256 (k)
__global__ __launch_bounds__(256) void prep_w(const float* __restrict__ w,
                                              unsigned short* __restrict__ wt) {
    int n = blockIdx.x;
    int k = threadIdx.x;
    wt[n * K_FEATS + k] = f2bf(w[k * N_FEATS + n]);
}

// ---------------- GEMM: sup(bf16) = x @ W via MFMA ----------------
// Block 256 = 4 waves. Block tile: 128 rows x 128 cols.
// Wave wv covers rows [wv*32, wv*32+32) (2 m-tiles) x all 128 cols (8 n-tiles).
__global__ __launch_bounds__(256) void gcn_gemm_mfma(const float* __restrict__ x,
                                                     const unsigned short* __restrict__ wt,
                                                     unsigned short* __restrict__ sup, int M) {
    // A tile: 128 rows x 32 k, bf16, row stride 40 (80 B: 16B-aligned, bank-spread)
    __shared__ __align__(16) unsigned short As[128 * 40];

    const int tid  = threadIdx.x;
    const int wv   = tid >> 6;
    const int lane = tid & 63;
    const int l15  = lane & 15;
    const int quad = lane >> 4;
    const int row0 = blockIdx.x * 128;

    float4v acc[2][8];
#pragma unroll
    for (int mt = 0; mt < 2; mt++)
#pragma unroll
        for (int nt = 0; nt < 8; nt++) acc[mt][nt] = (float4v)(0.f);

    for (int k0 = 0; k0 < K_FEATS; k0 += 32) {
        // stage A: 128 rows x 32 k fp32 -> bf16 LDS. 1024 float4 / 256 thr = 4 each.
#pragma unroll
        for (int l = 0; l < 4; l++) {
            int f   = tid + l * 256;     // float4 index
            int r   = f >> 3;            // 8 float4 per row
            int k4  = f & 7;
            int grow = row0 + r;
            float4 v = make_float4(0.f, 0.f, 0.f, 0.f);
            if (grow < M) v = *(const float4*)(x + (long)grow * K_FEATS + k0 + k4 * 4);
            unsigned int p0 = (unsigned int)f2bf(v.x) | ((unsigned int)f2bf(v.y) << 16);
            unsigned int p1 = (unsigned int)f2bf(v.z) | ((unsigned int)f2bf(v.w) << 16);
            *(uint2*)(&As[r * 40 + k4 * 4]) = make_uint2(p0, p1);
        }
        __syncthreads();

        // A fragments (2 m-tiles) from LDS
        short8 afrag[2];
#pragma unroll
        for (int mt = 0; mt < 2; mt++) {
            afrag[mt] = *(const short8*)(&As[(wv * 32 + mt * 16 + l15) * 40 + quad * 8]);
        }
        // B fragments (8 n-tiles) straight from global Wt (64 KB, cache-hot)
        short8 bfrag[8];
#pragma unroll
        for (int nt = 0; nt < 8; nt++) {
            bfrag[nt] = *(const short8*)(wt + (nt * 16 + l15) * K_FEATS + k0 + quad * 8);
        }
#pragma unroll
        for (int mt = 0; mt < 2; mt++)
#pragma unroll
            for (int nt = 0; nt < 8; nt++)
                acc[mt][nt] = __builtin_amdgcn_mfma_f32_16x16x32_bf16(
                    afrag[mt], bfrag[nt], acc[mt][nt], 0, 0, 0);
        __syncthreads();
    }

    // epilogue: D[row=(quad*4+reg)][col=l15] per tile -> sup bf16
#pragma unroll
    for (int mt = 0; mt < 2; mt++) {
#pragma unroll
        for (int reg = 0; reg < 4; reg++) {
            int grow = row0 + wv * 32 + mt * 16 + quad * 4 + reg;
            if (grow < M) {
#pragma unroll
                for (int nt = 0; nt < 8; nt++) {
                    sup[(long)grow * N_FEATS + nt * 16 + l15] = f2bf(acc[mt][nt][reg]);
                }
            }
        }
    }
}

// ---------------- counting sort by edge_row (unchanged from R2) ----------------
__global__ __launch_bounds__(256) void zero_counts(int* __restrict__ counts, int M) {
    int i = blockIdx.x * 256 + threadIdx.x;
    if (i <= M) counts[i] = 0;
}

__global__ __launch_bounds__(256) void hist_rows(const int* __restrict__ erow,
                                                 int* __restrict__ counts, int E) {
    int e = blockIdx.x * 256 + threadIdx.x;
    if (e < E) atomicAdd(&counts[erow[e]], 1);
}

__global__ __launch_bounds__(1024) void scan_blocks(const int* __restrict__ counts,
                                                    int* __restrict__ tmp_ex,
                                                    int* __restrict__ blocksums, int M) {
    __shared__ int sm[1024];
    int t = threadIdx.x;
    int idx = blockIdx.x * 1024 + t;
    int v = (idx < M) ? counts[idx] : 0;
    sm[t] = v;
    __syncthreads();
#pragma unroll
    for (int s = 1; s < 1024; s <<= 1) {
        int a = (t >= s) ? sm[t - s] : 0;
        __syncthreads();
        sm[t] += a;
        __syncthreads();
    }
    if (idx < M) tmp_ex[idx] = sm[t] - v;
    if (t == 1023) blocksums[blockIdx.x] = sm[1023];
}

__global__ __launch_bounds__(1024) void scan_sums(int* __restrict__ blocksums, int nb) {
    __shared__ int sm[1024];
    int t = threadIdx.x;
    int v = (t < nb) ? blocksums[t] : 0;
    sm[t] = v;
    __syncthreads();
#pragma unroll
    for (int s = 1; s < 1024; s <<= 1) {
        int a = (t >= s) ? sm[t - s] : 0;
        __syncthreads();
        sm[t] += a;
        __syncthreads();
    }
    if (t < nb) blocksums[t] = sm[t] - v;
}

__global__ __launch_bounds__(256) void add_offsets(int* __restrict__ off0,
                                                   int* __restrict__ off1,
                                                   const int* __restrict__ blocksums, int M) {
    int i = blockIdx.x * 256 + threadIdx.x;
    if (i < M) {
        int v = off0[i] + blocksums[i >> 10];
        off0[i] = v;
        off1[i] = v;
    }
}

__global__ __launch_bounds__(256) void fill_sorted(const int* __restrict__ erow,
                                                   const int* __restrict__ ecol,
                                                   const float* __restrict__ eval_,
                                                   int* __restrict__ cursor,
                                                   int2* __restrict__ sedge, int E) {
    int e = blockIdx.x * 256 + threadIdx.x;
    if (e < E) {
        int r = erow[e];
        int p = atomicAdd(&cursor[r], 1);
        sedge[p] = make_int2(ecol[e], __float_as_int(eval_[e]));
    }
}

// ---------------- SpMM: wave per row, bf16 sup gather, no atomics ----------------
__global__ __launch_bounds__(256) void gcn_spmm(const int* __restrict__ off0,
                                                const int* __restrict__ off1,
                                                const int2* __restrict__ sedge,
                                                const unsigned short* __restrict__ sup,
                                                const float* __restrict__ b,
                                                float* __restrict__ out, int M) {
    int row  = blockIdx.x * 4 + (threadIdx.x >> 6);
    int lane = threadIdx.x & 63;
    if (row >= M) return;
    int s = off0[row], e = off1[row];
    const unsigned int* sup32 = (const unsigned int*)sup;   // 2 bf16 per uint
    float2 acc = make_float2(0.f, 0.f);
    int i = s;
    for (; i + 1 < e; i += 2) {
        int2 e0 = sedge[i];
        int2 e1 = sedge[i + 1];
        float v0 = __int_as_float(e0.y);
        float v1 = __int_as_float(e1.y);
        unsigned int u0 = sup32[(long)e0.x * 64 + lane];
        unsigned int u1 = sup32[(long)e1.x * 64 + lane];
        acc.x += v0 * __uint_as_float(u0 << 16);
        acc.y += v0 * __uint_as_float(u0 & 0xFFFF0000u);
        acc.x += v1 * __uint_as_float(u1 << 16);
        acc.y += v1 * __uint_as_float(u1 & 0xFFFF0000u);
    }
    if (i < e) {
        int2 e0 = sedge[i];
        float v0 = __int_as_float(e0.y);
        unsigned int u0 = sup32[(long)e0.x * 64 + lane];
        acc.x += v0 * __uint_as_float(u0 << 16);
        acc.y += v0 * __uint_as_float(u0 & 0xFFFF0000u);
    }
    float2 bb = ((const float2*)b)[lane];
    ((float2*)out)[(long)row * 64 + lane] = make_float2(acc.x + bb.x, acc.y + bb.y);
}

extern "C" void kernel_launch(void* const* d_in, const int* in_sizes, int n_in,
                              void* d_out, int out_size, void* d_ws, size_t ws_size,
                              hipStream_t stream) {
    const float* x     = (const float*)d_in[0];
    const int*   erow  = (const int*)d_in[1];
    const int*   ecol  = (const int*)d_in[2];
    const float* eval_ = (const float*)d_in[3];
    const float* w     = (const float*)d_in[4];
    const float* b     = (const float*)d_in[5];
    float* out = (float*)d_out;

    const int M = in_sizes[0] / K_FEATS;   // 100000
    const int E = in_sizes[1];             // 1600000

    // workspace layout (16B aligned)
    size_t o_sup  = 0;                                              // bf16 sup
    size_t o_wt   = o_sup  + (((size_t)M * N_FEATS * 2 + 15) & ~15ul);
    size_t o_off0 = o_wt   + (size_t)K_FEATS * N_FEATS * 2;         // 64 KB
    size_t o_off1 = o_off0 + (((size_t)(M + 1) * 4 + 15) & ~15ul);
    size_t o_edge = o_off1 + (((size_t)(M + 1) * 4 + 15) & ~15ul);
    size_t o_bs   = o_edge + ((size_t)E * 8);
    (void)o_bs;

    unsigned short* sup   = (unsigned short*)((char*)d_ws + o_sup);
    unsigned short* wt    = (unsigned short*)((char*)d_ws + o_wt);
    int*            off0  = (int*)((char*)d_ws + o_off0);
    int*            off1  = (int*)((char*)d_ws + o_off1);
    int2*           sedge = (int2*)((char*)d_ws + o_edge);
    int*            bsums = (int*)((char*)d_ws + o_bs);

    // W -> Wt[n][k] bf16
    prep_w<<<N_FEATS, 256, 0, stream>>>(w, wt);

    // sup = bf16(x @ W)
    gcn_gemm_mfma<<<(M + 127) / 128, 256, 0, stream>>>(x, wt, sup, M);

    // counting sort edges by destination row
    int nb = (M + 1023) / 1024;
    zero_counts<<<(M + 256) / 256, 256, 0, stream>>>(off1, M);
    hist_rows<<<(E + 255) / 256, 256, 0, stream>>>(erow, off1, E);
    scan_blocks<<<nb, 1024, 0, stream>>>(off1, off0, bsums, M);
    scan_sums<<<1, 1024, 0, stream>>>(bsums, nb);
    add_offsets<<<(M + 255) / 256, 256, 0, stream>>>(off0, off1, bsums, M);
    fill_sorted<<<(E + 255) / 256, 256, 0, stream>>>(erow, ecol, eval_, off1, sedge, E);

    // out[row] = sum(val * sup[col]) + b
    gcn_spmm<<<(M + 3) / 4, 256, 0, stream>>>(off0, off1, sedge, sup, b, out, M);
}